// Round 2
// baseline (157.008 us; speedup 1.0000x reference)
//
#include <hip/hip_runtime.h>
#include <hip/hip_bf16.h>

#define B_ 128
#define L_ 196
#define D_ 1024

typedef __attribute__((ext_vector_type(8))) short short8v;
typedef __attribute__((ext_vector_type(4))) float f32x4;
typedef unsigned short ushort_t;

// d_ws layout (bytes), all 256-aligned. Total ≈ 60.3 MB (same as round 1).
#define OFF_ATTBF   0UL          // 25088*1024*2 = 51,380,224
#define OFF_WBF     51380224UL   // 1024*1024*2  =  2,097,152
#define OFF_A2      53477376UL   // 128*2048*2   =    524,288   [x|h] bf16
#define OFF_W2      54001664UL   // 1024*2048*2  =  4,194,304   [Wi|Wh] bf16
#define OFF_C       58195968UL   // 128*1024*4   =    524,288   c[b,e] fp32
#define OFF_SPART   58720256UL   // 25088*16*4   =  1,605,632   score partials

__device__ inline unsigned short f2bf(float f) {
  unsigned int u = __float_as_uint(f);
  unsigned int r = (u + 0x7fffu + ((u >> 16) & 1u)) >> 16;
  return (unsigned short)r;
}

// ---------------- convert: fp32 -> bf16 staging buffers ----------------
__global__ void convert_kernel(const float* __restrict__ att, const float* __restrict__ Wa,
                               const float* __restrict__ x,   const float* __restrict__ h,
                               const float* __restrict__ Wi,  const float* __restrict__ Wh,
                               ushort_t* __restrict__ att_bf, ushort_t* __restrict__ W_bf,
                               ushort_t* __restrict__ A2,     ushort_t* __restrict__ W2) {
  const int n0 = (B_*L_*D_)/4;
  const int n1 = (D_*D_)/4;
  const int n2 = (B_*D_)/4;
  const int total = n0 + n1 + 2*n2 + 2*n1;
  for (int idx = blockIdx.x*blockDim.x + threadIdx.x; idx < total;
       idx += gridDim.x*blockDim.x) {
    const float4* src; ushort_t* dst;
    int i = idx;
    if (i < n0)               { src = (const float4*)att + i; dst = att_bf + (size_t)i*4; }
    else if ((i -= n0) < n1)  { src = (const float4*)Wa  + i; dst = W_bf  + (size_t)i*4; }
    else if ((i -= n1) < n2)  { int b = i>>8, k4 = i&255; src = (const float4*)x  + i; dst = A2 + b*2048 + k4*4; }
    else if ((i -= n2) < n2)  { int b = i>>8, k4 = i&255; src = (const float4*)h  + i; dst = A2 + b*2048 + 1024 + k4*4; }
    else if ((i -= n2) < n1)  { int e = i>>8, k4 = i&255; src = (const float4*)Wi + i; dst = W2 + e*2048 + k4*4; }
    else { i -= n1;             int e = i>>8, k4 = i&255; src = (const float4*)Wh + i; dst = W2 + e*2048 + 1024 + k4*4; }
    float4 v = *src;
    ushort4 o; o.x = f2bf(v.x); o.y = f2bf(v.y); o.z = f2bf(v.z); o.w = f2bf(v.w);
    *(ushort4*)dst = o;
  }
}

// ---------------- small c-matrix GEMM (128x128 tile, 2-phase; unchanged) ----------------
__device__ inline void stage_tile(const ushort_t* __restrict__ g, int row0, int K, int k0,
                                  ushort_t* ldst, int t) {
  #pragma unroll
  for (int it = 0; it < 4; ++it) {
    int linear = it*4096 + t*16;
    int r = linear >> 7;
    int c = (t & 7) ^ (r & 7);
    const ushort_t* src = g + (size_t)(row0 + r)*K + k0 + c*8;
    ushort_t* dst = ldst + ((it*4096 + ((t & 192) << 4)) >> 1);
    __builtin_amdgcn_global_load_lds((const __attribute__((address_space(1))) void*)src,
                                     (__attribute__((address_space(3))) void*)dst,
                                     16, 0, 0);
  }
}

__device__ inline short8v ldfrag(const ushort_t* tile, int row, int c) {
  int phys = c ^ (row & 7);
  return *(const short8v*)(tile + row*64 + phys*8);
}

__global__ __launch_bounds__(256) void gemm_c_kernel(
    const ushort_t* __restrict__ Amat, const ushort_t* __restrict__ Bmat, int K,
    const float* __restrict__ ba, const float* __restrict__ bh, const float* __restrict__ bi,
    float* __restrict__ outc) {
  __shared__ ushort_t lds[32768];
  int bid = blockIdx.x;
  int m0 = 0, e0 = (bid & 7)*128;
  int t = threadIdx.x, lane = t & 63, w = t >> 6;
  int wm = w >> 1, we = w & 1;
  int lrow = lane & 15;
  int lk = lane >> 4;

  f32x4 acc[4][4];
  #pragma unroll
  for (int i = 0; i < 4; ++i)
    #pragma unroll
    for (int j = 0; j < 4; ++j) acc[i][j] = (f32x4){0.f, 0.f, 0.f, 0.f};

  stage_tile(Amat, m0, K, 0, lds, t);
  stage_tile(Bmat, e0, K, 0, lds + 8192, t);
  __syncthreads();

  int nk = K >> 6;
  for (int kt = 0; kt < nk; ++kt) {
    int cur = kt & 1;
    if (kt + 1 < nk) {
      stage_tile(Amat, m0, K, (kt+1) << 6, lds + (cur^1)*16384, t);
      stage_tile(Bmat, e0, K, (kt+1) << 6, lds + (cur^1)*16384 + 8192, t);
    }
    const ushort_t* At = lds + cur*16384;
    const ushort_t* Bt = At + 8192;
    #pragma unroll
    for (int hh = 0; hh < 2; ++hh) {
      short8v af[4], bfv[4];
      #pragma unroll
      for (int i = 0; i < 4; ++i) af[i]  = ldfrag(At, wm*64 + i*16 + lrow, hh*4 + lk);
      #pragma unroll
      for (int j = 0; j < 4; ++j) bfv[j] = ldfrag(Bt, we*64 + j*16 + lrow, hh*4 + lk);
      #pragma unroll
      for (int i = 0; i < 4; ++i)
        #pragma unroll
        for (int j = 0; j < 4; ++j)
          acc[i][j] = __builtin_amdgcn_mfma_f32_16x16x32_bf16(af[i], bfv[j], acc[i][j], 0, 0, 0);
    }
    __syncthreads();
  }

  #pragma unroll
  for (int i = 0; i < 4; ++i) {
    int m = m0 + wm*64 + i*16 + lk*4;
    #pragma unroll
    for (int j = 0; j < 4; ++j) {
      int e = e0 + we*64 + j*16 + lrow;
      float bsum = ba[e] + bh[e] + bi[e];
      #pragma unroll
      for (int r = 0; r < 4; ++r)
        outc[(m + r)*1024 + e] = acc[i][j][r] + bsum;
    }
  }
}

// ---------------- 256x256 8-phase score GEMM (T3+T4+T5) ----------------
__device__ inline short8v ldfrag2(const ushort_t* tile, int row, int c) {
  int phys = c ^ (row & 7);
  return *(const short8v*)(tile + row*64 + phys*8);   // ds_read_b128, 2-way max
}

// Stage one half-tile (128 rows x 64 cols bf16 = 16 KB); 2 global_load_lds/thread.
// LDS dest is linear (wave-uniform base + lane*16); source pre-swizzled so that
// logical chunk c lives at phys chunk c^(row&7) (matches ldfrag2).
__device__ inline void stage_half(const ushort_t* __restrict__ g, int row0, int Kdim,
                                  int kt, int half, ushort_t* lds_tile, int t, int w) {
  #pragma unroll
  for (int it2 = 0; it2 < 2; ++it2) {
    int linear = it2*8192 + t*16;          // byte offset within the 16KB half
    int r = linear >> 7;                   // 0..127
    int pc = (linear >> 4) & 7;
    int c = pc ^ (r & 7);
    const ushort_t* src = g + (size_t)(row0 + half*128 + r)*Kdim + kt*64 + c*8;
    ushort_t* dst = lds_tile + half*8192 + it2*4096 + w*512;   // elems; wave-uniform
    __builtin_amdgcn_global_load_lds((const __attribute__((address_space(1))) void*)src,
                                     (__attribute__((address_space(3))) void*)dst,
                                     16, 0, 0);
  }
}

#define SB0()   __builtin_amdgcn_sched_barrier(0)
#define BARR()  __builtin_amdgcn_s_barrier()
#define LGKM0() asm volatile("s_waitcnt lgkmcnt(0)" ::: "memory")
#define VM6()   asm volatile("s_waitcnt vmcnt(6)" ::: "memory")

// Fragment rows: i=0..3 -> lo half (rows wm*64+i*16), i=4..7 -> hi half (128+wm*64+i*16).
// This keeps "lo consumed by ph1, hi by ph3" true for EVERY wave (restage safety).
#define RD_A_LO(base) { _Pragma("unroll") for (int i_=0;i_<4;++i_) { int rr = wm*64 + i_*16 + lrow; \
    a[i_][0]=ldfrag2(base, rr, lk); a[i_][1]=ldfrag2(base, rr, 4+lk);} }
#define RD_A_HI(base) { _Pragma("unroll") for (int i_=0;i_<4;++i_) { int rr = 128 + wm*64 + i_*16 + lrow; \
    a[i_][0]=ldfrag2(base, rr, lk); a[i_][1]=ldfrag2(base, rr, 4+lk);} }
#define RD_B_LO(base) { _Pragma("unroll") for (int j_=0;j_<2;++j_) { int rr = wn*64 + j_*16 + lrow; \
    b[j_][0]=ldfrag2(base, rr, lk); b[j_][1]=ldfrag2(base, rr, 4+lk);} }
#define RD_B_HI(base) { _Pragma("unroll") for (int j_=0;j_<2;++j_) { int rr = wn*64 + (2+j_)*16 + lrow; \
    b[2+j_][0]=ldfrag2(base, rr, lk); b[2+j_][1]=ldfrag2(base, rr, 4+lk);} }

#define MFMAQ(I0, J0) { _Pragma("unroll") for (int i_=0;i_<4;++i_) { _Pragma("unroll") for (int j_=0;j_<2;++j_) { \
    acc[(I0)+i_][(J0)+j_] = __builtin_amdgcn_mfma_f32_16x16x32_bf16(a[i_][0], b[(J0)+j_][0], acc[(I0)+i_][(J0)+j_], 0,0,0); \
    acc[(I0)+i_][(J0)+j_] = __builtin_amdgcn_mfma_f32_16x16x32_bf16(a[i_][1], b[(J0)+j_][1], acc[(I0)+i_][(J0)+j_], 0,0,0); } } }

#define PH_TAIL(I0, J0) SB0(); BARR(); LGKM0(); SB0(); \
    __builtin_amdgcn_s_setprio(1); MFMAQ(I0, J0); __builtin_amdgcn_s_setprio(0); SB0(); BARR();

__global__ __launch_bounds__(512, 2) void gemm_score_kernel(
    const ushort_t* __restrict__ Amat, const ushort_t* __restrict__ Bmat,
    const float* __restrict__ cmat, const float* __restrict__ wd,
    float* __restrict__ spart) {
  __shared__ ushort_t lds[65536];   // 128 KB: A0 B0 A1 B1, 32KB each
  const int K = 1024, nk = 16, NI = 8;
  int bid = blockIdx.x;
  int swz = (bid & 7)*49 + (bid >> 3);     // 392 % 8 == 0 -> bijective
  int m_blk = swz >> 2, e_blk = swz & 3;
  int m0 = m_blk*256, e0 = e_blk*256;
  int t = (int)threadIdx.x, lane = t & 63, w = t >> 6;
  int wm = w >> 2, wn = w & 3;
  int lrow = lane & 15, lk = lane >> 4;

  ushort_t* A0_ = lds;
  ushort_t* B0_ = lds + 16384;
  ushort_t* A1_ = lds + 32768;
  ushort_t* B1_ = lds + 49152;

  f32x4 acc[8][4];
  #pragma unroll
  for (int i = 0; i < 8; ++i)
    #pragma unroll
    for (int j = 0; j < 4; ++j) acc[i][j] = (f32x4){0.f, 0.f, 0.f, 0.f};
  short8v a[4][2], b[4][2];

  // prologue: K-tile 0 complete (4 HT) + 3 halves of K-tile 1 => 14 loads; vmcnt(6)
  // drains exactly K-tile 0, leaves {A1lo,B1lo,B1hi} in flight (steady state).
  stage_half(Amat, m0, K, 0, 0, A0_, t, w);
  stage_half(Amat, m0, K, 0, 1, A0_, t, w);
  stage_half(Bmat, e0, K, 0, 0, B0_, t, w);
  stage_half(Bmat, e0, K, 0, 1, B0_, t, w);
  stage_half(Amat, m0, K, 1, 0, A1_, t, w);
  stage_half(Bmat, e0, K, 1, 0, B1_, t, w);
  stage_half(Bmat, e0, K, 1, 1, B1_, t, w);
  VM6(); SB0(); BARR();

  for (int itr = 0; itr < NI; ++itr) {
    int kt0 = 2*itr;
    int kc2 = (kt0+2 < nk) ? kt0+2 : nk-1;   // clamped tail restage (never read)
    int kc3 = (kt0+3 < nk) ? kt0+3 : nk-1;
    // ph1: q0 of kt0
    RD_A_LO(A0_); RD_B_LO(B0_);
    stage_half(Amat, m0, K, kt0+1, 1, A1_, t, w);     // A_hi(kt0+1)
    PH_TAIL(0,0);
    // ph2: q1
    RD_B_HI(B0_);
    stage_half(Amat, m0, K, kc2, 0, A0_, t, w);       // A_lo(kt0+2)
    PH_TAIL(0,2);
    // ph3: q2
    RD_A_HI(A0_);
    stage_half(Bmat, e0, K, kc2, 0, B0_, t, w);       // B_lo(kt0+2)
    PH_TAIL(4,0);
    // ph4: q3 (+vmcnt: completes K-tile kt0+1 for ph5)
    stage_half(Bmat, e0, K, kc2, 1, B0_, t, w);       // B_hi(kt0+2)
    VM6();
    PH_TAIL(4,2);
    // ph5: q0 of kt0+1
    RD_A_LO(A1_); RD_B_LO(B1_);
    stage_half(Amat, m0, K, kc2, 1, A0_, t, w);       // A_hi(kt0+2)
    PH_TAIL(0,0);
    // ph6: q1
    RD_B_HI(B1_);
    stage_half(Amat, m0, K, kc3, 0, A1_, t, w);       // A_lo(kt0+3)
    PH_TAIL(0,2);
    // ph7: q2
    RD_A_HI(A1_);
    stage_half(Bmat, e0, K, kc3, 0, B1_, t, w);       // B_lo(kt0+3)
    PH_TAIL(4,0);
    // ph8: q3 (+vmcnt: completes K-tile kt0+2 for next ph1)
    stage_half(Bmat, e0, K, kc3, 1, B1_, t, w);       // B_hi(kt0+3)
    VM6();
    PH_TAIL(4,2);
  }

  // epilogue: partial score = sum_e tanh(acc + c[b,e]) * wd[e], deterministic
  #pragma unroll
  for (int i = 0; i < 8; ++i) {
    int mbase = m0 + (i>>2)*128 + wm*64 + (i&3)*16 + lk*4;
    #pragma unroll
    for (int r = 0; r < 4; ++r) {
      int m = mbase + r;
      int bb = (int)((unsigned)m / 196u);
      float partial = 0.f;
      #pragma unroll
      for (int j = 0; j < 4; ++j) {
        int e = e0 + wn*64 + j*16 + lrow;
        float v = acc[i][j][r] + cmat[bb*1024 + e];
        float ex = __expf(2.f*v);
        partial += (1.f - 2.f/(ex + 1.f)) * wd[e];
      }
      partial += __shfl_xor(partial, 1);
      partial += __shfl_xor(partial, 2);
      partial += __shfl_xor(partial, 4);
      partial += __shfl_xor(partial, 8);
      if (lrow == 0) spart[(size_t)m*16 + e_blk*4 + wn] = partial;
    }
  }
}

// ---------------- finalize: softmax over L, weighted sum of att ----------------
__global__ __launch_bounds__(256) void finalize_kernel(const float* __restrict__ att,
                                                       const float* __restrict__ spart,
                                                       float* __restrict__ out) {
  int b  = blockIdx.x >> 1;
  int dh = blockIdx.x & 1;
  int t  = threadIdx.x;
  __shared__ float wls[L_];
  __shared__ float red[8];

  float s = -1e30f;
  if (t < L_) {
    const float* sp = spart + (size_t)(b*L_ + t)*16;
    float sum = 0.f;
    #pragma unroll
    for (int p = 0; p < 16; ++p) sum += sp[p];
    s = sum;
  }
  float m = s;
  #pragma unroll
  for (int off = 1; off < 64; off <<= 1) m = fmaxf(m, __shfl_xor(m, off));
  if ((t & 63) == 0) red[t >> 6] = m;
  __syncthreads();
  m = fmaxf(fmaxf(red[0], red[1]), fmaxf(red[2], red[3]));
  float p = (t < L_) ? __expf(s - m) : 0.f;
  float ssum = p;
  #pragma unroll
  for (int off = 1; off < 64; off <<= 1) ssum += __shfl_xor(ssum, off);
  if ((t & 63) == 0) red[4 + (t >> 6)] = ssum;
  __syncthreads();
  float tot = red[4] + red[5] + red[6] + red[7];
  if (t < L_) wls[t] = p / tot;
  __syncthreads();

  int d = dh*512 + t*2;
  const float* abase = att + (size_t)b*L_*D_ + d;
  float a0 = 0.f, a1 = 0.f;
  #pragma unroll 4
  for (int l = 0; l < L_; ++l) {
    float wv = wls[l];
    float2 av = *(const float2*)(abase + (size_t)l*D_);
    a0 += wv*av.x; a1 += wv*av.y;
  }
  float2 o; o.x = a0; o.y = a1;
  *(float2*)(out + (size_t)b*D_ + d) = o;
}

extern "C" void kernel_launch(void* const* d_in, const int* in_sizes, int n_in,
                              void* d_out, int out_size, void* d_ws, size_t ws_size,
                              hipStream_t stream) {
  (void)in_sizes; (void)n_in; (void)out_size; (void)ws_size;
  const float* x   = (const float*)d_in[0];
  const float* att = (const float*)d_in[1];
  const float* h   = (const float*)d_in[2];
  const float* Wa  = (const float*)d_in[3];
  const float* ba  = (const float*)d_in[4];
  const float* Wh  = (const float*)d_in[5];
  const float* bh  = (const float*)d_in[6];
  const float* Wi  = (const float*)d_in[7];
  const float* bi  = (const float*)d_in[8];
  const float* wd  = (const float*)d_in[9];
  // d_in[10] = b_d2d: softmax shift-invariant, unused

  char* ws = (char*)d_ws;
  ushort_t* att_bf = (ushort_t*)(ws + OFF_ATTBF);
  ushort_t* W_bf   = (ushort_t*)(ws + OFF_WBF);
  ushort_t* A2     = (ushort_t*)(ws + OFF_A2);
  ushort_t* W2     = (ushort_t*)(ws + OFF_W2);
  float*    cmat   = (float*)(ws + OFF_C);
  float*    spart  = (float*)(ws + OFF_SPART);
  float*    out    = (float*)d_out;

  hipLaunchKernelGGL(convert_kernel, dim3(2048), dim3(256), 0, stream,
                     att, Wa, x, h, Wi, Wh, att_bf, W_bf, A2, W2);
  hipLaunchKernelGGL(gemm_c_kernel, dim3(8), dim3(256), 0, stream,
                     A2, W2, 2048, ba, bh, bi, cmat);
  hipLaunchKernelGGL(gemm_score_kernel, dim3(392), dim3(512), 0, stream,
                     att_bf, W_bf, cmat, wd, spart);
  hipLaunchKernelGGL(finalize_kernel, dim3(256), dim3(256), 0, stream,
                     att, spart, out);
}

// Round 3
// 129.514 us; speedup vs baseline: 1.2123x; 1.2123x over previous
//
#include <hip/hip_runtime.h>
#include <hip/hip_bf16.h>

#define B_ 128
#define L_ 196
#define D_ 1024

typedef __attribute__((ext_vector_type(8))) short short8v;
typedef __attribute__((ext_vector_type(4))) float f32x4;
typedef unsigned short ushort_t;

// d_ws layout (bytes). Max footprint 60,293,120 (< round-1/2 proven 60.3MB).
#define OFF_ATTBF   0UL          // 25088*1024*2 = 51,380,224
#define OFF_WBF     51380224UL   // 1024*1024*2  =  2,097,152
#define OFF_A2      53477376UL   // 128*2048*2   =    524,288   [x|h] bf16
#define OFF_W2      54001664UL   // 1024*2048*2  =  4,194,304   [Wi|Wh] bf16 (ends 58,195,968)
#define OFF_SPART   53477376UL   // 16*25088*4   =  1,605,632   (aliases A2/W2: dead before score)
#define OFF_CPART   58195968UL   // 4*128*1024*4 =  2,097,152   c partials (ends 60,293,120)

__device__ inline unsigned short f2bf(float f) {
  unsigned int u = __float_as_uint(f);
  unsigned int r = (u + 0x7fffu + ((u >> 16) & 1u)) >> 16;
  return (unsigned short)r;
}

// ---------------- convert: fp32 -> bf16 staging buffers ----------------
__global__ void convert_kernel(const float* __restrict__ att, const float* __restrict__ Wa,
                               const float* __restrict__ x,   const float* __restrict__ h,
                               const float* __restrict__ Wi,  const float* __restrict__ Wh,
                               ushort_t* __restrict__ att_bf, ushort_t* __restrict__ W_bf,
                               ushort_t* __restrict__ A2,     ushort_t* __restrict__ W2) {
  const int n0 = (B_*L_*D_)/4;
  const int n1 = (D_*D_)/4;
  const int n2 = (B_*D_)/4;
  const int total = n0 + n1 + 2*n2 + 2*n1;
  for (int idx = blockIdx.x*blockDim.x + threadIdx.x; idx < total;
       idx += gridDim.x*blockDim.x) {
    const float4* src; ushort_t* dst;
    int i = idx;
    if (i < n0)               { src = (const float4*)att + i; dst = att_bf + (size_t)i*4; }
    else if ((i -= n0) < n1)  { src = (const float4*)Wa  + i; dst = W_bf  + (size_t)i*4; }
    else if ((i -= n1) < n2)  { int b = i>>8, k4 = i&255; src = (const float4*)x  + i; dst = A2 + b*2048 + k4*4; }
    else if ((i -= n2) < n2)  { int b = i>>8, k4 = i&255; src = (const float4*)h  + i; dst = A2 + b*2048 + 1024 + k4*4; }
    else if ((i -= n2) < n1)  { int e = i>>8, k4 = i&255; src = (const float4*)Wi + i; dst = W2 + e*2048 + k4*4; }
    else { i -= n1;             int e = i>>8, k4 = i&255; src = (const float4*)Wh + i; dst = W2 + e*2048 + 1024 + k4*4; }
    float4 v = *src;
    ushort4 o; o.x = f2bf(v.x); o.y = f2bf(v.y); o.z = f2bf(v.z); o.w = f2bf(v.w);
    *(ushort4*)dst = o;
  }
}

// ---------------- c-matrix GEMM, split-K x4 (grid 32) ----------------
__device__ inline void stage_tile(const ushort_t* __restrict__ g, int row0, int Kld, int k0,
                                  ushort_t* ldst, int t) {
  #pragma unroll
  for (int it = 0; it < 4; ++it) {
    int linear = it*4096 + t*16;
    int r = linear >> 7;
    int c = (t & 7) ^ (r & 7);
    const ushort_t* src = g + (size_t)(row0 + r)*Kld + k0 + c*8;
    ushort_t* dst = ldst + ((it*4096 + ((t & 192) << 4)) >> 1);
    __builtin_amdgcn_global_load_lds((const __attribute__((address_space(1))) void*)src,
                                     (__attribute__((address_space(3))) void*)dst,
                                     16, 0, 0);
  }
}

__device__ inline short8v ldfrag(const ushort_t* tile, int row, int c) {
  int phys = c ^ (row & 7);
  return *(const short8v*)(tile + row*64 + phys*8);
}

__global__ __launch_bounds__(256) void gemm_c_kernel(
    const ushort_t* __restrict__ Amat, const ushort_t* __restrict__ Bmat,
    float* __restrict__ cpart) {
  __shared__ ushort_t lds[32768];
  int bid = blockIdx.x;
  int e0 = (bid & 7)*128;
  int kc = bid >> 3;               // 0..3, K-chunk of 512
  int kbeg = kc*512;
  const int Kld = 2048;
  int t = threadIdx.x, lane = t & 63, w = t >> 6;
  int wm = w >> 1, we = w & 1;
  int lrow = lane & 15;
  int lk = lane >> 4;

  f32x4 acc[4][4];
  #pragma unroll
  for (int i = 0; i < 4; ++i)
    #pragma unroll
    for (int j = 0; j < 4; ++j) acc[i][j] = (f32x4){0.f, 0.f, 0.f, 0.f};

  stage_tile(Amat, 0,  Kld, kbeg, lds, t);
  stage_tile(Bmat, e0, Kld, kbeg, lds + 8192, t);
  __syncthreads();

  const int nk = 8;                // 512 / 64
  for (int kt = 0; kt < nk; ++kt) {
    int cur = kt & 1;
    if (kt + 1 < nk) {
      stage_tile(Amat, 0,  Kld, kbeg + ((kt+1) << 6), lds + (cur^1)*16384, t);
      stage_tile(Bmat, e0, Kld, kbeg + ((kt+1) << 6), lds + (cur^1)*16384 + 8192, t);
    }
    const ushort_t* At = lds + cur*16384;
    const ushort_t* Bt = At + 8192;
    #pragma unroll
    for (int hh = 0; hh < 2; ++hh) {
      short8v af[4], bfv[4];
      #pragma unroll
      for (int i = 0; i < 4; ++i) af[i]  = ldfrag(At, wm*64 + i*16 + lrow, hh*4 + lk);
      #pragma unroll
      for (int j = 0; j < 4; ++j) bfv[j] = ldfrag(Bt, we*64 + j*16 + lrow, hh*4 + lk);
      #pragma unroll
      for (int i = 0; i < 4; ++i)
        #pragma unroll
        for (int j = 0; j < 4; ++j)
          acc[i][j] = __builtin_amdgcn_mfma_f32_16x16x32_bf16(af[i], bfv[j], acc[i][j], 0, 0, 0);
    }
    __syncthreads();
  }

  float* outc = cpart + (size_t)kc*131072;   // [128][1024] raw partial (no bias)
  #pragma unroll
  for (int i = 0; i < 4; ++i) {
    int m = wm*64 + i*16 + lk*4;
    #pragma unroll
    for (int j = 0; j < 4; ++j) {
      int e = e0 + we*64 + j*16 + lrow;
      #pragma unroll
      for (int r = 0; r < 4; ++r)
        outc[(m + r)*1024 + e] = acc[i][j][r];
    }
  }
}

// ---------------- 256x256 8-phase score GEMM ----------------
__device__ inline short8v ldfrag2(const ushort_t* tile, int row, int c) {
  int phys = c ^ (row & 7);
  return *(const short8v*)(tile + row*64 + phys*8);   // ds_read_b128, 2-way max
}

// One half-tile (128 rows x 64 cols = 16KB): 2 x global_load_lds per thread.
// lanebase precomputed: g + (row0 + (t>>3))*1024 + ((t&7)^((t>>3)&7))*8
#define STAGE(lanebase, half, kt, ldsT) { \
    const ushort_t* s0_ = (lanebase) + (half)*131072 + (kt)*64; \
    ushort_t* d0_ = (ldsT) + (half)*8192 + w*512; \
    __builtin_amdgcn_global_load_lds((const __attribute__((address_space(1))) void*)s0_, \
                                     (__attribute__((address_space(3))) void*)d0_, 16, 0, 0); \
    __builtin_amdgcn_global_load_lds((const __attribute__((address_space(1))) void*)(s0_ + 65536), \
                                     (__attribute__((address_space(3))) void*)(d0_ + 4096), 16, 0, 0); }

#define BARR()  __builtin_amdgcn_s_barrier()
#define VM6()   asm volatile("s_waitcnt vmcnt(6)" ::: "memory")

#define RD_A_LO(base) { _Pragma("unroll") for (int i_=0;i_<4;++i_) { int rr = wm*64 + i_*16 + lrow; \
    a[i_][0]=ldfrag2(base, rr, lk); a[i_][1]=ldfrag2(base, rr, 4+lk);} }
#define RD_A_HI(base) { _Pragma("unroll") for (int i_=0;i_<4;++i_) { int rr = 128 + wm*64 + i_*16 + lrow; \
    a[i_][0]=ldfrag2(base, rr, lk); a[i_][1]=ldfrag2(base, rr, 4+lk);} }
#define RD_B_LO(base) { _Pragma("unroll") for (int j_=0;j_<2;++j_) { int rr = wn*64 + j_*16 + lrow; \
    b[j_][0]=ldfrag2(base, rr, lk); b[j_][1]=ldfrag2(base, rr, 4+lk);} }
#define RD_B_HI(base) { _Pragma("unroll") for (int j_=0;j_<2;++j_) { int rr = wn*64 + (2+j_)*16 + lrow; \
    b[2+j_][0]=ldfrag2(base, rr, lk); b[2+j_][1]=ldfrag2(base, rr, 4+lk);} }

// k-major: 8 independent MFMAs per k-slot (no back-to-back same-acc deps)
#define MFMAQ(I0, J0) { _Pragma("unroll") for (int k_=0;k_<2;++k_) { \
    _Pragma("unroll") for (int i_=0;i_<4;++i_) { _Pragma("unroll") for (int j_=0;j_<2;++j_) { \
      acc[(I0)+i_][(J0)+j_] = __builtin_amdgcn_mfma_f32_16x16x32_bf16(a[i_][k_], b[(J0)+j_][k_], acc[(I0)+i_][(J0)+j_], 0,0,0); } } } }

// two barriers per phase; lgkm waits left to the compiler (fine-grained per-MFMA)
#define PH_TAIL(I0, J0) BARR(); \
    __builtin_amdgcn_s_setprio(1); MFMAQ(I0, J0); __builtin_amdgcn_s_setprio(0); BARR();

__global__ __launch_bounds__(512, 2) void gemm_score_kernel(
    const ushort_t* __restrict__ Amat, const ushort_t* __restrict__ Bmat,
    const float* __restrict__ cpart,
    const float* __restrict__ ba, const float* __restrict__ bh, const float* __restrict__ bi,
    const float* __restrict__ wd,
    float* __restrict__ spart) {
  __shared__ ushort_t lds[65536];   // 128 KB: A0 B0 A1 B1, 32KB each
  __shared__ float c_lds[768];      // [3][256]: c+biases for this block's (bb,e) range
  const int nk = 16, NI = 8;
  int bid = blockIdx.x;
  int swz = (bid & 7)*49 + (bid >> 3);     // 392 % 8 == 0 -> bijective XCD swizzle
  int m_blk = swz >> 2, e_blk = swz & 3;
  int m0 = m_blk*256, e0 = e_blk*256;
  int t = (int)threadIdx.x, lane = t & 63, w = t >> 6;
  int wm = w >> 2, wn = w & 3;
  int lrow = lane & 15, lk = lane >> 4;

  // precompute c_lds = biases + sum of 4 K-partials
  int bb0 = m0 / 196;
  for (int idx = t; idx < 768; idx += 512) {
    int bb = bb0 + (idx >> 8);
    int e  = e0 + (idx & 255);
    float v = ba[e] + bh[e] + bi[e];
    if (bb < 128) {
      v += cpart[bb*1024 + e] + cpart[131072 + bb*1024 + e]
         + cpart[262144 + bb*1024 + e] + cpart[393216 + bb*1024 + e];
    }
    c_lds[idx] = v;
  }

  // per-lane staging base pointers (row r0 = t>>3, chunk c0 = (t&7)^(r0&7))
  int r0 = t >> 3;
  int c0 = (t & 7) ^ (r0 & 7);
  const ushort_t* aBase = Amat + (size_t)(m0 + r0)*1024 + c0*8;
  const ushort_t* bBase = Bmat + (size_t)(e0 + r0)*1024 + c0*8;

  ushort_t* A0_ = lds;
  ushort_t* B0_ = lds + 16384;
  ushort_t* A1_ = lds + 32768;
  ushort_t* B1_ = lds + 49152;

  f32x4 acc[8][4];
  #pragma unroll
  for (int i = 0; i < 8; ++i)
    #pragma unroll
    for (int j = 0; j < 4; ++j) acc[i][j] = (f32x4){0.f, 0.f, 0.f, 0.f};
  short8v a[4][2], b[4][2];

  // prologue: K-tile 0 (4 half-tiles) + 3 halves of K-tile 1 = 14 loads; vmcnt(6)
  // drains exactly K-tile 0, leaves {A1hi-slot empty, A1lo,B1lo,B1hi in flight}.
  STAGE(aBase, 0, 0, A0_);
  STAGE(aBase, 1, 0, A0_);
  STAGE(bBase, 0, 0, B0_);
  STAGE(bBase, 1, 0, B0_);
  STAGE(aBase, 0, 1, A1_);
  STAGE(bBase, 0, 1, B1_);
  STAGE(bBase, 1, 1, B1_);
  VM6(); BARR();

  for (int itr = 0; itr < NI; ++itr) {
    int kt0 = 2*itr;
    int kc2 = (kt0+2 < nk) ? kt0+2 : nk-1;   // clamped tail restage (never read)
    int kc3 = (kt0+3 < nk) ? kt0+3 : nk-1;
    // ph1: q0 of kt0
    RD_A_LO(A0_); RD_B_LO(B0_);
    STAGE(aBase, 1, kt0+1, A1_);
    PH_TAIL(0,0);
    // ph2: q1
    RD_B_HI(B0_);
    STAGE(aBase, 0, kc2, A0_);
    PH_TAIL(0,2);
    // ph3: q2
    RD_A_HI(A0_);
    STAGE(bBase, 0, kc2, B0_);
    PH_TAIL(4,0);
    // ph4: q3 (+vmcnt: completes K-tile kt0+1 for ph5)
    STAGE(bBase, 1, kc2, B0_);
    VM6();
    PH_TAIL(4,2);
    // ph5: q0 of kt0+1
    RD_A_LO(A1_); RD_B_LO(B1_);
    STAGE(aBase, 1, kc2, A0_);
    PH_TAIL(0,0);
    // ph6: q1
    RD_B_HI(B1_);
    STAGE(aBase, 0, kc3, A1_);
    PH_TAIL(0,2);
    // ph7: q2
    RD_A_HI(A1_);
    STAGE(bBase, 0, kc3, B1_);
    PH_TAIL(4,0);
    // ph8: q3 (+vmcnt: completes K-tile kt0+2 for next ph1)
    STAGE(bBase, 1, kc3, B1_);
    VM6();
    PH_TAIL(4,2);
  }

  // epilogue: partial score = sum_e tanh(acc + c) * wd[e]; spart[p][m], float4 stores
  int p = e_blk*4 + wn;
  #pragma unroll
  for (int i = 0; i < 8; ++i) {
    int mbase = m0 + (i>>2)*128 + wm*64 + (i&3)*16 + lk*4;
    f32x4 ps;
    #pragma unroll
    for (int r = 0; r < 4; ++r) {
      int m = mbase + r;
      int bb = (int)((unsigned)m / 196u);
      float partial = 0.f;
      #pragma unroll
      for (int j = 0; j < 4; ++j) {
        int ee = wn*64 + j*16 + lrow;
        float v = acc[i][j][r] + c_lds[(bb - bb0)*256 + ee];
        float ex = __expf(2.f*v);
        partial += (1.f - 2.f/(ex + 1.f)) * wd[e0 + ee];
      }
      partial += __shfl_xor(partial, 1);
      partial += __shfl_xor(partial, 2);
      partial += __shfl_xor(partial, 4);
      partial += __shfl_xor(partial, 8);
      ps[r] = partial;
    }
    if (lrow == 0) *(f32x4*)(spart + (size_t)p*25088 + mbase) = ps;
  }
}

// ---------------- finalize: softmax over L, weighted sum of bf16 att ----------------
__global__ __launch_bounds__(256) void finalize_kernel(const ushort_t* __restrict__ att_bf,
                                                       const float* __restrict__ spart,
                                                       float* __restrict__ out) {
  int b  = blockIdx.x >> 1;
  int dh = blockIdx.x & 1;
  int t  = threadIdx.x;
  __shared__ float wls[L_];
  __shared__ float red[8];

  float s = -1e30f;
  if (t < L_) {
    int m = b*L_ + t;
    float sum = 0.f;
    #pragma unroll
    for (int p = 0; p < 16; ++p) sum += spart[p*25088 + m];
    s = sum;                       // b_d2d omitted: softmax shift-invariant
  }
  float mx = s;
  #pragma unroll
  for (int off = 1; off < 64; off <<= 1) mx = fmaxf(mx, __shfl_xor(mx, off));
  if ((t & 63) == 0) red[t >> 6] = mx;
  __syncthreads();
  mx = fmaxf(fmaxf(red[0], red[1]), fmaxf(red[2], red[3]));
  float pr = (t < L_) ? __expf(s - mx) : 0.f;
  float ssum = pr;
  #pragma unroll
  for (int off = 1; off < 64; off <<= 1) ssum += __shfl_xor(ssum, off);
  if ((t & 63) == 0) red[4 + (t >> 6)] = ssum;
  __syncthreads();
  float tot = red[4] + red[5] + red[6] + red[7];
  if (t < L_) wls[t] = pr / tot;
  __syncthreads();

  int d = dh*512 + t*2;
  const ushort_t* abase = att_bf + (size_t)b*L_*D_ + d;
  float a0 = 0.f, a1 = 0.f;
  #pragma unroll 4
  for (int l = 0; l < L_; ++l) {
    float wv = wls[l];
    unsigned int v = *(const unsigned int*)(abase + (size_t)l*D_);
    float lo = __uint_as_float(v << 16);
    float hi = __uint_as_float(v & 0xffff0000u);
    a0 += wv*lo; a1 += wv*hi;
  }
  float2 o; o.x = a0; o.y = a1;
  *(float2*)(out + (size_t)b*D_ + d) = o;
}

extern "C" void kernel_launch(void* const* d_in, const int* in_sizes, int n_in,
                              void* d_out, int out_size, void* d_ws, size_t ws_size,
                              hipStream_t stream) {
  (void)in_sizes; (void)n_in; (void)out_size; (void)ws_size;
  const float* x   = (const float*)d_in[0];
  const float* att = (const float*)d_in[1];
  const float* h   = (const float*)d_in[2];
  const float* Wa  = (const float*)d_in[3];
  const float* ba  = (const float*)d_in[4];
  const float* Wh  = (const float*)d_in[5];
  const float* bh  = (const float*)d_in[6];
  const float* Wi  = (const float*)d_in[7];
  const float* bi  = (const float*)d_in[8];
  const float* wd  = (const float*)d_in[9];
  // d_in[10] = b_d2d: softmax shift-invariant, unused

  char* ws = (char*)d_ws;
  ushort_t* att_bf = (ushort_t*)(ws + OFF_ATTBF);
  ushort_t* W_bf   = (ushort_t*)(ws + OFF_WBF);
  ushort_t* A2     = (ushort_t*)(ws + OFF_A2);
  ushort_t* W2     = (ushort_t*)(ws + OFF_W2);
  float*    cpart  = (float*)(ws + OFF_CPART);
  float*    spart  = (float*)(ws + OFF_SPART);
  float*    out    = (float*)d_out;

  hipLaunchKernelGGL(convert_kernel, dim3(2048), dim3(256), 0, stream,
                     att, Wa, x, h, Wi, Wh, att_bf, W_bf, A2, W2);
  hipLaunchKernelGGL(gemm_c_kernel, dim3(32), dim3(256), 0, stream,
                     A2, W2, cpart);
  hipLaunchKernelGGL(gemm_score_kernel, dim3(392), dim3(512), 0, stream,
                     att_bf, W_bf, cpart, ba, bh, bi, wd, spart);
  hipLaunchKernelGGL(finalize_kernel, dim3(256), dim3(256), 0, stream,
                     att_bf, spart, out);
}

// Round 4
// 125.695 us; speedup vs baseline: 1.2491x; 1.0304x over previous
//
#include <hip/hip_runtime.h>
#include <hip/hip_bf16.h>

#define B_ 128
#define L_ 196
#define D_ 1024

typedef __attribute__((ext_vector_type(8))) short short8v;
typedef __attribute__((ext_vector_type(4))) float f32x4;
typedef unsigned short ushort_t;

// d_ws layout (bytes). Max footprint 60,293,120.
#define OFF_ATTBF   0UL          // 25088*1024*2 = 51,380,224
#define OFF_WBF     51380224UL   // 1024*1024*2  =  2,097,152
#define OFF_A2      53477376UL   // 128*2048*2   =    524,288   [x|h] bf16
#define OFF_W2      54001664UL   // 1024*2048*2  =  4,194,304   [Wi|Wh] bf16
#define OFF_SPART   53477376UL   // 16*25088*4   =  1,605,632   (aliases A2/W2: dead before score)
#define OFF_CPART   58195968UL   // 4*128*1024*4 =  2,097,152   c partials

__device__ inline unsigned short f2bf(float f) {
  unsigned int u = __float_as_uint(f);
  unsigned int r = (u + 0x7fffu + ((u >> 16) & 1u)) >> 16;
  return (unsigned short)r;
}

// ---------------- convert: fp32 -> bf16 staging buffers ----------------
__global__ void convert_kernel(const float* __restrict__ att, const float* __restrict__ Wa,
                               const float* __restrict__ x,   const float* __restrict__ h,
                               const float* __restrict__ Wi,  const float* __restrict__ Wh,
                               ushort_t* __restrict__ att_bf, ushort_t* __restrict__ W_bf,
                               ushort_t* __restrict__ A2,     ushort_t* __restrict__ W2) {
  const int n0 = (B_*L_*D_)/4;
  const int n1 = (D_*D_)/4;
  const int n2 = (B_*D_)/4;
  const int total = n0 + n1 + 2*n2 + 2*n1;
  for (int idx = blockIdx.x*blockDim.x + threadIdx.x; idx < total;
       idx += gridDim.x*blockDim.x) {
    const float4* src; ushort_t* dst;
    int i = idx;
    if (i < n0)               { src = (const float4*)att + i; dst = att_bf + (size_t)i*4; }
    else if ((i -= n0) < n1)  { src = (const float4*)Wa  + i; dst = W_bf  + (size_t)i*4; }
    else if ((i -= n1) < n2)  { int b = i>>8, k4 = i&255; src = (const float4*)x  + i; dst = A2 + b*2048 + k4*4; }
    else if ((i -= n2) < n2)  { int b = i>>8, k4 = i&255; src = (const float4*)h  + i; dst = A2 + b*2048 + 1024 + k4*4; }
    else if ((i -= n2) < n1)  { int e = i>>8, k4 = i&255; src = (const float4*)Wi + i; dst = W2 + e*2048 + k4*4; }
    else { i -= n1;             int e = i>>8, k4 = i&255; src = (const float4*)Wh + i; dst = W2 + e*2048 + 1024 + k4*4; }
    float4 v = *src;
    ushort4 o; o.x = f2bf(v.x); o.y = f2bf(v.y); o.z = f2bf(v.z); o.w = f2bf(v.w);
    *(ushort4*)dst = o;
  }
}

// ---------------- c-matrix GEMM, split-K x4 (grid 32) ----------------
__device__ inline void stage_tile(const ushort_t* __restrict__ g, int row0, int Kld, int k0,
                                  ushort_t* ldst, int t) {
  #pragma unroll
  for (int it = 0; it < 4; ++it) {
    int linear = it*4096 + t*16;
    int r = linear >> 7;
    int c = (t & 7) ^ (r & 7);
    const ushort_t* src = g + (size_t)(row0 + r)*Kld + k0 + c*8;
    ushort_t* dst = ldst + ((it*4096 + ((t & 192) << 4)) >> 1);
    __builtin_amdgcn_global_load_lds((const __attribute__((address_space(1))) void*)src,
                                     (__attribute__((address_space(3))) void*)dst,
                                     16, 0, 0);
  }
}

__device__ inline short8v ldfrag(const ushort_t* tile, int row, int c) {
  int phys = c ^ (row & 7);
  return *(const short8v*)(tile + row*64 + phys*8);
}

__global__ __launch_bounds__(256) void gemm_c_kernel(
    const ushort_t* __restrict__ Amat, const ushort_t* __restrict__ Bmat,
    float* __restrict__ cpart) {
  __shared__ ushort_t lds[32768];
  int bid = blockIdx.x;
  int e0 = (bid & 7)*128;
  int kc = bid >> 3;               // 0..3, K-chunk of 512
  int kbeg = kc*512;
  const int Kld = 2048;
  int t = threadIdx.x, lane = t & 63, w = t >> 6;
  int wm = w >> 1, we = w & 1;
  int lrow = lane & 15;
  int lk = lane >> 4;

  f32x4 acc[4][4];
  #pragma unroll
  for (int i = 0; i < 4; ++i)
    #pragma unroll
    for (int j = 0; j < 4; ++j) acc[i][j] = (f32x4){0.f, 0.f, 0.f, 0.f};

  stage_tile(Amat, 0,  Kld, kbeg, lds, t);
  stage_tile(Bmat, e0, Kld, kbeg, lds + 8192, t);
  __syncthreads();

  const int nk = 8;                // 512 / 64
  for (int kt = 0; kt < nk; ++kt) {
    int cur = kt & 1;
    if (kt + 1 < nk) {
      stage_tile(Amat, 0,  Kld, kbeg + ((kt+1) << 6), lds + (cur^1)*16384, t);
      stage_tile(Bmat, e0, Kld, kbeg + ((kt+1) << 6), lds + (cur^1)*16384 + 8192, t);
    }
    const ushort_t* At = lds + cur*16384;
    const ushort_t* Bt = At + 8192;
    #pragma unroll
    for (int hh = 0; hh < 2; ++hh) {
      short8v af[4], bfv[4];
      #pragma unroll
      for (int i = 0; i < 4; ++i) af[i]  = ldfrag(At, wm*64 + i*16 + lrow, hh*4 + lk);
      #pragma unroll
      for (int j = 0; j < 4; ++j) bfv[j] = ldfrag(Bt, we*64 + j*16 + lrow, hh*4 + lk);
      #pragma unroll
      for (int i = 0; i < 4; ++i)
        #pragma unroll
        for (int j = 0; j < 4; ++j)
          acc[i][j] = __builtin_amdgcn_mfma_f32_16x16x32_bf16(af[i], bfv[j], acc[i][j], 0, 0, 0);
    }
    __syncthreads();
  }

  float* outc = cpart + (size_t)kc*131072;   // [128][1024] raw partial (no bias)
  #pragma unroll
  for (int i = 0; i < 4; ++i) {
    int m = wm*64 + i*16 + lk*4;
    #pragma unroll
    for (int j = 0; j < 4; ++j) {
      int e = e0 + we*64 + j*16 + lrow;
      #pragma unroll
      for (int r = 0; r < 4; ++r)
        outc[(m + r)*1024 + e] = acc[i][j][r];
    }
  }
}

// ---------------- 256x256 8-phase score GEMM (single-barrier phases) ----------------
__device__ inline short8v ldfrag2(const ushort_t* tile, int row, int c) {
  int phys = c ^ (row & 7);
  return *(const short8v*)(tile + row*64 + phys*8);   // ds_read_b128, 2-way max
}

#define STAGE(lanebase, half, kt, ldsT) { \
    const ushort_t* s0_ = (lanebase) + (half)*131072 + (kt)*64; \
    ushort_t* d0_ = (ldsT) + (half)*8192 + w*512; \
    __builtin_amdgcn_global_load_lds((const __attribute__((address_space(1))) void*)s0_, \
                                     (__attribute__((address_space(3))) void*)d0_, 16, 0, 0); \
    __builtin_amdgcn_global_load_lds((const __attribute__((address_space(1))) void*)(s0_ + 65536), \
                                     (__attribute__((address_space(3))) void*)(d0_ + 4096), 16, 0, 0); }

#define BARR()  __builtin_amdgcn_s_barrier()
#define VM6()   asm volatile("s_waitcnt vmcnt(6)" ::: "memory")

#define RD_A_LO(base) { _Pragma("unroll") for (int i_=0;i_<4;++i_) { int rr = wm*64 + i_*16 + lrow; \
    a[i_][0]=ldfrag2(base, rr, lk); a[i_][1]=ldfrag2(base, rr, 4+lk);} }
#define RD_A_HI(base) { _Pragma("unroll") for (int i_=0;i_<4;++i_) { int rr = 128 + wm*64 + i_*16 + lrow; \
    a[i_][0]=ldfrag2(base, rr, lk); a[i_][1]=ldfrag2(base, rr, 4+lk);} }
#define RD_B_LO(base) { _Pragma("unroll") for (int j_=0;j_<2;++j_) { int rr = wn*64 + j_*16 + lrow; \
    b[j_][0]=ldfrag2(base, rr, lk); b[j_][1]=ldfrag2(base, rr, 4+lk);} }
#define RD_B_HI(base) { _Pragma("unroll") for (int j_=0;j_<2;++j_) { int rr = wn*64 + (2+j_)*16 + lrow; \
    b[2+j_][0]=ldfrag2(base, rr, lk); b[2+j_][1]=ldfrag2(base, rr, 4+lk);} }

#define MFMAQ(I0, J0) { _Pragma("unroll") for (int k_=0;k_<2;++k_) { \
    _Pragma("unroll") for (int i_=0;i_<4;++i_) { _Pragma("unroll") for (int j_=0;j_<2;++j_) { \
      acc[(I0)+i_][(J0)+j_] = __builtin_amdgcn_mfma_f32_16x16x32_bf16(a[i_][k_], b[(J0)+j_][k_], acc[(I0)+i_][(J0)+j_], 0,0,0); } } } }

// ONE barrier per phase; LDS drain of next phase overlaps this phase's MFMA.
// Safety: every STAGE targets a buffer last-read exactly 2 phases earlier.
#define PH(I0, J0) BARR(); \
    __builtin_amdgcn_s_setprio(1); MFMAQ(I0, J0); __builtin_amdgcn_s_setprio(0);

__global__ __launch_bounds__(512, 2) void gemm_score_kernel(
    const ushort_t* __restrict__ Amat, const ushort_t* __restrict__ Bmat,
    const float* __restrict__ cpart,
    const float* __restrict__ ba, const float* __restrict__ bh, const float* __restrict__ bi,
    const float* __restrict__ wd,
    float* __restrict__ spart) {
  __shared__ ushort_t lds[65536];   // 128 KB: A0 B0 A1 B1, 32KB each
  __shared__ float c_lds[768];      // [3][256]: c+biases for this block's (bb,e) range
  const int nk = 16, NI = 8;
  int bid = blockIdx.x;
  int swz = (bid & 7)*49 + (bid >> 3);     // 392 % 8 == 0 -> bijective XCD swizzle
  int m_blk = swz >> 2, e_blk = swz & 3;
  int m0 = m_blk*256, e0 = e_blk*256;
  int t = (int)threadIdx.x, lane = t & 63, w = t >> 6;
  int wm = w >> 2, wn = w & 3;
  int lrow = lane & 15, lk = lane >> 4;

  // c_lds = biases + sum of 4 K-partials
  int bb0 = m0 / 196;
  for (int idx = t; idx < 768; idx += 512) {
    int bb = bb0 + (idx >> 8);
    int e  = e0 + (idx & 255);
    float v = ba[e] + bh[e] + bi[e];
    if (bb < 128) {
      v += cpart[bb*1024 + e] + cpart[131072 + bb*1024 + e]
         + cpart[262144 + bb*1024 + e] + cpart[393216 + bb*1024 + e];
    }
    c_lds[idx] = v;
  }

  // per-lane staging base pointers (row r0 = t>>3, chunk c0 = (t&7)^(r0&7))
  int r0 = t >> 3;
  int c0 = (t & 7) ^ (r0 & 7);
  const ushort_t* aBase = Amat + (size_t)(m0 + r0)*1024 + c0*8;
  const ushort_t* bBase = Bmat + (size_t)(e0 + r0)*1024 + c0*8;

  ushort_t* A0_ = lds;
  ushort_t* B0_ = lds + 16384;
  ushort_t* A1_ = lds + 32768;
  ushort_t* B1_ = lds + 49152;

  f32x4 acc[8][4];
  #pragma unroll
  for (int i = 0; i < 8; ++i)
    #pragma unroll
    for (int j = 0; j < 4; ++j) acc[i][j] = (f32x4){0.f, 0.f, 0.f, 0.f};
  short8v a[4][2], b[4][2];

  // prologue: K-tile 0 (4 halves) + {A1lo,B1lo,B1hi} of K-tile 1 = 14 loads;
  // vmcnt(6) drains K-tile 0 exactly, leaves 3 half-tiles in flight.
  STAGE(aBase, 0, 0, A0_);
  STAGE(aBase, 1, 0, A0_);
  STAGE(bBase, 0, 0, B0_);
  STAGE(bBase, 1, 0, B0_);
  STAGE(aBase, 0, 1, A1_);
  STAGE(bBase, 0, 1, B1_);
  STAGE(bBase, 1, 1, B1_);
  VM6(); BARR();

  for (int itr = 0; itr < NI; ++itr) {
    int kt0 = 2*itr;
    int kc2 = (kt0+2 < nk) ? kt0+2 : nk-1;   // clamped tail restage (never read)
    int kc3 = (kt0+3 < nk) ? kt0+3 : nk-1;
    // ph1: reads kt0 q0; stages A1hi(kt0+1) [buf1-hi last read ph7-prev: gap 2]
    RD_A_LO(A0_); RD_B_LO(B0_);
    STAGE(aBase, 1, kt0+1, A1_);
    PH(0,0);
    // ph2: reads B0hi
    RD_B_HI(B0_);
    PH(0,2);
    // ph3: reads A0hi; stages A0lo,B0lo(kt0+2) [last read ph1: gap 2]
    RD_A_HI(A0_);
    STAGE(aBase, 0, kc2, A0_);
    STAGE(bBase, 0, kc2, B0_);
    PH(4,0);
    // ph4: stages B0hi(kt0+2) [last read ph2: gap 2]; vmcnt completes kt0+1
    STAGE(bBase, 1, kc2, B0_);
    VM6();
    PH(4,2);
    // ph5: reads kt0+1 q0; stages A0hi(kt0+2) [last read ph3: gap 2]
    RD_A_LO(A1_); RD_B_LO(B1_);
    STAGE(aBase, 1, kc2, A0_);
    PH(0,0);
    // ph6: reads B1hi
    RD_B_HI(B1_);
    PH(0,2);
    // ph7: reads A1hi; stages A1lo,B1lo(kt0+3) [last read ph5: gap 2]
    RD_A_HI(A1_);
    STAGE(aBase, 0, kc3, A1_);
    STAGE(bBase, 0, kc3, B1_);
    PH(4,0);
    // ph8: stages B1hi(kt0+3) [last read ph6: gap 2]; vmcnt completes kt0+2
    STAGE(bBase, 1, kc3, B1_);
    VM6();
    PH(4,2);
  }

  // epilogue: partial score = sum_e tanh(acc + c) * wd[e]; spart[p][m], float4 stores
  int p = e_blk*4 + wn;
  #pragma unroll
  for (int i = 0; i < 8; ++i) {
    int mbase = m0 + (i>>2)*128 + wm*64 + (i&3)*16 + lk*4;
    f32x4 ps;
    #pragma unroll
    for (int r = 0; r < 4; ++r) {
      int m = mbase + r;
      int bb = (int)((unsigned)m / 196u);
      float partial = 0.f;
      #pragma unroll
      for (int j = 0; j < 4; ++j) {
        int ee = wn*64 + j*16 + lrow;
        float v = acc[i][j][r] + c_lds[(bb - bb0)*256 + ee];
        float ex = __expf(2.f*v);
        partial += (1.f - 2.f/(ex + 1.f)) * wd[e0 + ee];
      }
      partial += __shfl_xor(partial, 1);
      partial += __shfl_xor(partial, 2);
      partial += __shfl_xor(partial, 4);
      partial += __shfl_xor(partial, 8);
      ps[r] = partial;
    }
    if (lrow == 0) *(f32x4*)(spart + (size_t)p*25088 + mbase) = ps;
  }
}

// ---------------- finalize: softmax over L, weighted sum of bf16 att ----------------
__global__ __launch_bounds__(256) void finalize_kernel(const ushort_t* __restrict__ att_bf,
                                                       const float* __restrict__ spart,
                                                       float* __restrict__ out) {
  int b  = blockIdx.x >> 1;
  int dh = blockIdx.x & 1;
  int t  = threadIdx.x;
  __shared__ float wls[L_];
  __shared__ float red[8];

  float s = -1e30f;
  if (t < L_) {
    int m = b*L_ + t;
    float sum = 0.f;
    #pragma unroll
    for (int p = 0; p < 16; ++p) sum += spart[p*25088 + m];
    s = sum;                       // b_d2d omitted: softmax shift-invariant
  }
  float mx = s;
  #pragma unroll
  for (int off = 1; off < 64; off <<= 1) mx = fmaxf(mx, __shfl_xor(mx, off));
  if ((t & 63) == 0) red[t >> 6] = mx;
  __syncthreads();
  mx = fmaxf(fmaxf(red[0], red[1]), fmaxf(red[2], red[3]));
  float pr = (t < L_) ? __expf(s - mx) : 0.f;
  float ssum = pr;
  #pragma unroll
  for (int off = 1; off < 64; off <<= 1) ssum += __shfl_xor(ssum, off);
  if ((t & 63) == 0) red[4 + (t >> 6)] = ssum;
  __syncthreads();
  float tot = red[4] + red[5] + red[6] + red[7];
  if (t < L_) wls[t] = pr / tot;
  __syncthreads();

  int d = dh*512 + t*2;
  const ushort_t* abase = att_bf + (size_t)b*L_*D_ + d;
  float a0 = 0.f, a1 = 0.f;
  #pragma unroll 4
  for (int l = 0; l < L_; ++l) {
    float wv = wls[l];
    unsigned int v = *(const unsigned int*)(abase + (size_t)l*D_);
    float lo = __uint_as_float(v << 16);
    float hi = __uint_as_float(v & 0xffff0000u);
    a0 += wv*lo; a1 += wv*hi;
  }
  float2 o; o.x = a0; o.y = a1;
  *(float2*)(out + (size_t)b*D_ + d) = o;
}

extern "C" void kernel_launch(void* const* d_in, const int* in_sizes, int n_in,
                              void* d_out, int out_size, void* d_ws, size_t ws_size,
                              hipStream_t stream) {
  (void)in_sizes; (void)n_in; (void)out_size; (void)ws_size;
  const float* x   = (const float*)d_in[0];
  const float* att = (const float*)d_in[1];
  const float* h   = (const float*)d_in[2];
  const float* Wa  = (const float*)d_in[3];
  const float* ba  = (const float*)d_in[4];
  const float* Wh  = (const float*)d_in[5];
  const float* bh  = (const float*)d_in[6];
  const float* Wi  = (const float*)d_in[7];
  const float* bi  = (const float*)d_in[8];
  const float* wd  = (const float*)d_in[9];
  // d_in[10] = b_d2d: softmax shift-invariant, unused

  char* ws = (char*)d_ws;
  ushort_t* att_bf = (ushort_t*)(ws + OFF_ATTBF);
  ushort_t* W_bf   = (ushort_t*)(ws + OFF_WBF);
  ushort_t* A2     = (ushort_t*)(ws + OFF_A2);
  ushort_t* W2     = (ushort_t*)(ws + OFF_W2);
  float*    cpart  = (float*)(ws + OFF_CPART);
  float*    spart  = (float*)(ws + OFF_SPART);
  float*    out    = (float*)d_out;

  hipLaunchKernelGGL(convert_kernel, dim3(2048), dim3(256), 0, stream,
                     att, Wa, x, h, Wi, Wh, att_bf, W_bf, A2, W2);
  hipLaunchKernelGGL(gemm_c_kernel, dim3(32), dim3(256), 0, stream,
                     A2, W2, cpart);
  hipLaunchKernelGGL(gemm_score_kernel, dim3(392), dim3(512), 0, stream,
                     att_bf, W_bf, cpart, ba, bh, bi, wd, spart);
  hipLaunchKernelGGL(finalize_kernel, dim3(256), dim3(256), 0, stream,
                     att_bf, spart, out);
}